// Round 7
// baseline (648.167 us; speedup 1.0000x reference)
//
#include <hip/hip_runtime.h>
#include <math.h>

#define NV 20
#define NC 64
#define NSTATES (1u << 20)
#define TOPK 10
#define NBLK 256             // cooperative grid: 1 block per CU
#define NTHR 1024
#define NCAND (NBLK * TOPK)  // 2560
#define NB1F 256             // fallback stage-1 top-k blocks

// ---------------------------------------------------------------------------
// Distributed-flag grid barrier: arrival is ONE plain agent store to a
// per-block flag (no same-line RMW serialization); threads 0..255 poll one
// flag each. Fencing pattern identical to the R6 barrier that validated.
// flags[] zeroed by hipMemsetAsync before launch; gen = 1,2,3,...
// ---------------------------------------------------------------------------
__device__ __forceinline__ void gbar(unsigned* flags, unsigned gen) {
  __syncthreads();
  __threadfence();                         // drain this block's prior writes
  if (threadIdx.x == 0)
    __hip_atomic_store(&flags[blockIdx.x], gen, __ATOMIC_RELAXED,
                       __HIP_MEMORY_SCOPE_AGENT);
  if (threadIdx.x < NBLK) {
    while (__hip_atomic_load(&flags[threadIdx.x], __ATOMIC_RELAXED,
                             __HIP_MEMORY_SCOPE_AGENT) < gen) {
      __builtin_amdgcn_s_sleep(1);
    }
  }
  __threadfence();
  __syncthreads();
}

// ===========================================================================
// Cooperative mono-kernel. amdgpu_waves_per_eu(4,4) pins occupancy to
// 4 waves/EU (16 waves/CU = one 1024-thread block) so the compiler may use
// the full 128-VGPR budget -> gv[8] stays in registers (R5/R6 spilled at 52/56
// VGPRs under the default 8-waves/EU heuristic).
// All accumulation orders bitwise-identical to the validated R4 pipeline.
// ===========================================================================
template <bool ALB>
__global__
__attribute__((amdgpu_flat_work_group_size(NTHR, NTHR)))
__attribute__((amdgpu_waves_per_eu(4, 4)))
void k_all(
    const float* __restrict__ C,
    const float* __restrict__ beta,
    const float* __restrict__ gamma,
    float* __restrict__ costs,
    float* __restrict__ A,
    float* __restrict__ B,
    float* __restrict__ out,
    double* __restrict__ scal,
    unsigned long long* __restrict__ cand,
    unsigned* __restrict__ flags,
    unsigned* __restrict__ ctr) {

  __shared__ float4 tile[NTHR];            // 16 KB
  __shared__ float CT[17][NC];             // C columns 16..0
  __shared__ float lowT[8][NC];            // low-3-bit table (cols 19,18,17)
  __shared__ double dpart[16];
  __shared__ unsigned long long warr[16];
  __shared__ unsigned long long winS;
  __shared__ unsigned topi[TOPK];
  __shared__ float topc[TOPK];

  const int tid = threadIdx.x;
  const unsigned t = blockIdx.x * (unsigned)NTHR + (unsigned)tid;

  if (blockIdx.x == 0 && tid < 8) scal[tid] = 0.0;

  // ---- stage 0: costs + ph0 (chunked over constraints, 16 at a time) ----
  for (int e = tid; e < 17 * NC; e += NTHR) {
    int k = e / NC, c = e % NC;
    CT[k][c] = C[c * NV + (16 - k)];
  }
  for (int e = tid; e < 8 * NC; e += NTHR) {
    int m = e >> 6, c = e & 63;
    float v = 0.0f;
    if (m & 1) v += C[c * NV + 19];
    if (m & 2) v += C[c * NV + 18];
    if (m & 4) v += C[c * NV + 17];
    lowT[m][c] = v;
  }
  __syncthreads();

  float cost[4];
  #pragma unroll
  for (int s = 0; s < 4; ++s)
    cost[s] = 0.1f * (float)__popc(4u * t + (unsigned)s);
  const int m01 = (int)((t & 1u) << 2);

  #pragma unroll
  for (int cc = 0; cc < 4; ++cc) {
    float4 bb[4];
    #pragma unroll
    for (int q = 0; q < 4; ++q) bb[q] = make_float4(-1.f, -1.f, -1.f, -1.f);
    #pragma unroll
    for (int k = 0; k < 17; ++k) {
      float bf = (float)((t >> (k + 1)) & 1u);
      const float4* row = ((const float4*)(&CT[k][0])) + 4 * cc;
      #pragma unroll
      for (int q = 0; q < 4; ++q) {
        float4 cv = row[q];
        bb[q].x = fmaf(bf, cv.x, bb[q].x);
        bb[q].y = fmaf(bf, cv.y, bb[q].y);
        bb[q].z = fmaf(bf, cv.z, bb[q].z);
        bb[q].w = fmaf(bf, cv.w, bb[q].w);
      }
    }
    #pragma unroll
    for (int s = 0; s < 4; ++s) {
      const float4* lrow = ((const float4*)(&lowT[m01 | s][0])) + 4 * cc;
      #pragma unroll
      for (int q = 0; q < 4; ++q) {
        float4 lv = lrow[q];
        float4 v;
        v.x = bb[q].x + lv.x; v.y = bb[q].y + lv.y;
        v.z = bb[q].z + lv.z; v.w = bb[q].w + lv.w;
        float r;
        r = fmaxf(v.x, 0.f); cost[s] = fmaf(r, r, cost[s]);
        r = fmaxf(v.y, 0.f); cost[s] = fmaf(r, r, cost[s]);
        r = fmaxf(v.z, 0.f); cost[s] = fmaf(r, r, cost[s]);
        r = fmaxf(v.w, 0.f); cost[s] = fmaf(r, r, cost[s]);
      }
    }
  }

  float g0 = gamma[0];
  ((float4*)costs)[t] = make_float4(cost[0], cost[1], cost[2], cost[3]);
  float4 pin_own;
  pin_own.x = 0x1p-10f * cosf(g0 * cost[0]);
  pin_own.y = 0x1p-10f * cosf(g0 * cost[1]);
  pin_own.z = 0x1p-10f * cosf(g0 * cost[2]);
  pin_own.w = 0x1p-10f * cosf(g0 * cost[3]);
  ((float4*)A)[t] = pin_own;

  gbar(flags, 1u);

  // ---- stages 1-3: fused phase+mixer ----
  float4 m2_own = make_float4(0.f, 0.f, 0.f, 0.f);
  #pragma unroll
  for (int L = 0; L < 3; ++L) {
    const float* pin = (L == 1) ? B : A;
    const bool pinAligned = (L == 1) ? ALB : true;
    float s = 0.1f * sinf(beta[L]);
    float prevscale = (L == 0) ? 1.0f : (float)(1.0 / sqrt(scal[L - 1]));

    tile[tid] = pin_own;
    float4 gv[8];
    #pragma unroll
    for (int p = 19; p >= 12; --p) {
      unsigned j4 = t ^ (1u << (p - 2));
      if (pinAligned) gv[19 - p] = ((const float4*)pin)[j4];
      else {
        gv[19 - p].x = pin[4u * j4 + 0]; gv[19 - p].y = pin[4u * j4 + 1];
        gv[19 - p].z = pin[4u * j4 + 2]; gv[19 - p].w = pin[4u * j4 + 3];
      }
    }
    __syncthreads();

    float4 nb = make_float4(0.f, 0.f, 0.f, 0.f);
    #pragma unroll
    for (int u = 0; u < 8; ++u) {
      nb.x += gv[u].x; nb.y += gv[u].y; nb.z += gv[u].z; nb.w += gv[u].w;
    }
    #pragma unroll
    for (int p = 11; p >= 2; --p) {
      float4 v = tile[tid ^ (1 << (p - 2))];
      nb.x += v.x; nb.y += v.y; nb.z += v.z; nb.w += v.w;
    }
    nb.x += pin_own.z; nb.y += pin_own.w; nb.z += pin_own.x; nb.w += pin_own.y;
    nb.x += pin_own.y; nb.y += pin_own.x; nb.z += pin_own.w; nb.w += pin_own.z;

    float4 m;
    m.x = prevscale * fmaf(s, nb.x, pin_own.x);
    m.y = prevscale * fmaf(s, nb.y, pin_own.y);
    m.z = prevscale * fmaf(s, nb.z, pin_own.z);
    m.w = prevscale * fmaf(s, nb.w, pin_own.w);

    double ss = (double)m.x * m.x + (double)m.y * m.y +
                (double)m.z * m.z + (double)m.w * m.w;
    #pragma unroll
    for (int off = 32; off > 0; off >>= 1) ss += __shfl_down(ss, off);
    if ((tid & 63) == 0) dpart[tid >> 6] = ss;
    __syncthreads();
    if (tid == 0) {
      double tt = 0.0;
      #pragma unroll
      for (int w = 0; w < 16; ++w) tt += dpart[w];
      atomicAdd(&scal[L], tt);
    }

    if (L < 2) {
      float gn = gamma[L + 1];
      float4 o;
      o.x = m.x * cosf(gn * cost[0]);
      o.y = m.y * cosf(gn * cost[1]);
      o.z = m.z * cosf(gn * cost[2]);
      o.w = m.w * cosf(gn * cost[3]);
      if (L == 0) {
        if (ALB) ((float4*)B)[t] = o;
        else {
          B[4u * t + 0] = o.x; B[4u * t + 1] = o.y;
          B[4u * t + 2] = o.z; B[4u * t + 3] = o.w;
        }
      } else {
        ((float4*)A)[t] = o;
      }
      pin_own = o;
    } else {
      m2_own = m;
    }
    gbar(flags, 2u + (unsigned)L);
  }

  // ---- stage 4: probs + per-block top-10 ----
  float scale2 = (float)(1.0 / sqrt(scal[2]));
  float4 pr;
  pr.x = m2_own.x * scale2; pr.x *= pr.x;
  pr.y = m2_own.y * scale2; pr.y *= pr.y;
  pr.z = m2_own.z * scale2; pr.z *= pr.z;
  pr.w = m2_own.w * scale2; pr.w *= pr.w;
  float* probs = out + 21;
  unsigned e0 = 4u * t;
  probs[e0 + 0] = pr.x; probs[e0 + 1] = pr.y;
  probs[e0 + 2] = pr.z; probs[e0 + 3] = pr.w;

  unsigned long long k[4];
  k[0] = ((unsigned long long)__float_as_uint(pr.x) << 32) | (unsigned long long)(0xFFFFFFFFu - (e0 + 0));
  k[1] = ((unsigned long long)__float_as_uint(pr.y) << 32) | (unsigned long long)(0xFFFFFFFFu - (e0 + 1));
  k[2] = ((unsigned long long)__float_as_uint(pr.z) << 32) | (unsigned long long)(0xFFFFFFFFu - (e0 + 2));
  k[3] = ((unsigned long long)__float_as_uint(pr.w) << 32) | (unsigned long long)(0xFFFFFFFFu - (e0 + 3));

  for (int r = 0; r < TOPK; ++r) {
    unsigned long long loc = k[0];
    if (k[1] > loc) loc = k[1];
    if (k[2] > loc) loc = k[2];
    if (k[3] > loc) loc = k[3];
    #pragma unroll
    for (int off = 32; off > 0; off >>= 1) {
      unsigned long long o = __shfl_down(loc, off);
      if (o > loc) loc = o;
    }
    if ((tid & 63) == 0) warr[tid >> 6] = loc;
    __syncthreads();
    if (tid == 0) {
      unsigned long long win = warr[0];
      #pragma unroll
      for (int w = 1; w < 16; ++w) if (warr[w] > win) win = warr[w];
      winS = win;
      cand[blockIdx.x * TOPK + r] = win;
    }
    __syncthreads();
    unsigned long long win = winS;
    if (k[0] == win) k[0] = 0ull;
    if (k[1] == win) k[1] = 0ull;
    if (k[2] == win) k[2] = 0ull;
    if (k[3] == win) k[3] = 0ull;
    __syncthreads();
  }

  // ---- ticket: only block 0 continues; everyone else exits ----
  __threadfence();
  __syncthreads();
  if (tid == 0) atomicAdd(ctr, 1u);
  if (blockIdx.x != 0) return;
  if (tid == 0) {
    while (__hip_atomic_load(ctr, __ATOMIC_RELAXED,
                             __HIP_MEMORY_SCOPE_AGENT) < (unsigned)NBLK) {
      __builtin_amdgcn_s_sleep(1);
    }
  }
  __syncthreads();
  __threadfence();

  // ---- stage 5: block-0 merge + readout ----
  unsigned long long c2[3] = {0ull, 0ull, 0ull};
  #pragma unroll
  for (int u = 0; u < 3; ++u) {
    int j = tid + NTHR * u;
    if (j < NCAND) c2[u] = cand[j];
  }
  for (int r = 0; r < TOPK; ++r) {
    unsigned long long loc = c2[0];
    if (c2[1] > loc) loc = c2[1];
    if (c2[2] > loc) loc = c2[2];
    #pragma unroll
    for (int off = 32; off > 0; off >>= 1) {
      unsigned long long o = __shfl_down(loc, off);
      if (o > loc) loc = o;
    }
    if ((tid & 63) == 0) warr[tid >> 6] = loc;
    __syncthreads();
    if (tid == 0) {
      unsigned long long win = warr[0];
      #pragma unroll
      for (int w = 1; w < 16; ++w) if (warr[w] > win) win = warr[w];
      winS = win;
      topi[r] = 0xFFFFFFFFu - (unsigned)(win & 0xFFFFFFFFull);
    }
    __syncthreads();
    unsigned long long win = winS;
    if (c2[0] == win) c2[0] = 0ull;
    if (c2[1] == win) c2[1] = 0ull;
    if (c2[2] == win) c2[2] = 0ull;
    __syncthreads();
  }

  const unsigned S = NSTATES;
  if (tid < TOPK * NV) {
    int kk = tid / NV, vv = tid % NV;
    out[21 + S + (unsigned)tid] = (float)((topi[kk] >> (NV - 1 - vv)) & 1u);
  }
  if (tid < TOPK) {
    float c = costs[topi[tid]];
    topc[tid] = c;
    out[21 + S + TOPK * NV + (unsigned)tid] = c;
  }
  __syncthreads();
  if (tid == 0) {
    int best = 0;
    for (int kk = 1; kk < TOPK; ++kk)
      if (topc[kk] < topc[best]) best = kk;
    unsigned gi = topi[best];
    for (int vv = 0; vv < NV; ++vv)
      out[vv] = (float)((gi >> (NV - 1 - vv)) & 1u);
    out[NV] = topc[best];
  }
}

// ===========================================================================
// Fallback: validated R4 5-kernel pipeline (bitwise-identical outputs).
// ===========================================================================
__global__ __launch_bounds__(256) void k_costs(const float* __restrict__ C,
                                               float* __restrict__ costs,
                                               float* __restrict__ ph0,
                                               const float* __restrict__ gamma,
                                               double* __restrict__ scal,
                                               unsigned* __restrict__ ctr) {
    __shared__ float CT[NV][NC];
    __shared__ float lowT[8][NC];
    const int tid = threadIdx.x;
    if (blockIdx.x == 0) {
        if (tid < 8) scal[tid] = 0.0;
        if (tid == 8) *ctr = 0u;
    }
    for (int e = tid; e < NC * NV; e += 256) { int c = e / NV, j = e % NV; CT[j][c] = C[e]; }
    for (int e = tid; e < 8 * NC; e += 256) {
        int m = e >> 6, c = e & 63;
        float v = 0.0f;
        if (m & 1) v += C[c * NV + 19];
        if (m & 2) v += C[c * NV + 18];
        if (m & 4) v += C[c * NV + 17];
        lowT[m][c] = v;
    }
    __syncthreads();
    unsigned t = blockIdx.x * 256u + (unsigned)tid;
    float g0 = gamma[0];
    float4 b[16];
    #pragma unroll
    for (int q = 0; q < 16; ++q) b[q] = make_float4(-1.f, -1.f, -1.f, -1.f);
    #pragma unroll
    for (int k = 0; k < 17; ++k) {
        float bf = (float)((t >> k) & 1u);
        const float4* row = (const float4*)(&CT[16 - k][0]);
        #pragma unroll
        for (int q = 0; q < 16; ++q) {
            float4 cv = row[q];
            b[q].x = fmaf(bf, cv.x, b[q].x);
            b[q].y = fmaf(bf, cv.y, b[q].y);
            b[q].z = fmaf(bf, cv.z, b[q].z);
            b[q].w = fmaf(bf, cv.w, b[q].w);
        }
    }
    float res[8], ph[8];
    #pragma unroll
    for (int s = 0; s < 8; ++s) {
        unsigned i = t * 8u + (unsigned)s;
        float cost = 0.1f * (float)__popc(i);
        const float4* lrow = (const float4*)(&lowT[s][0]);
        #pragma unroll
        for (int q = 0; q < 16; ++q) {
            float4 lv = lrow[q];
            float4 v;
            v.x = b[q].x + lv.x; v.y = b[q].y + lv.y;
            v.z = b[q].z + lv.z; v.w = b[q].w + lv.w;
            float r;
            r = fmaxf(v.x, 0.f); cost = fmaf(r, r, cost);
            r = fmaxf(v.y, 0.f); cost = fmaf(r, r, cost);
            r = fmaxf(v.z, 0.f); cost = fmaf(r, r, cost);
            r = fmaxf(v.w, 0.f); cost = fmaf(r, r, cost);
        }
        res[s] = cost;
        ph[s] = 0x1p-10f * cosf(g0 * cost);
    }
    float4* co = (float4*)(costs + (size_t)t * 8u);
    co[0] = make_float4(res[0], res[1], res[2], res[3]);
    co[1] = make_float4(res[4], res[5], res[6], res[7]);
    float4* po = (float4*)(ph0 + (size_t)t * 8u);
    po[0] = make_float4(ph[0], ph[1], ph[2], ph[3]);
    po[1] = make_float4(ph[4], ph[5], ph[6], ph[7]);
}

template <int LAYER, bool ALIN, bool ALOUT>
__global__ __launch_bounds__(1024, 4) void k_mix(const float* __restrict__ pin,
                                                 const float* __restrict__ costs,
                                                 float* __restrict__ pout,
                                                 const float* __restrict__ gamma,
                                                 const float* __restrict__ beta,
                                                 double* __restrict__ scal) {
    __shared__ float4 tile[1024];
    __shared__ double dpart[16];
    const unsigned lq = threadIdx.x;
    const unsigned i4 = blockIdx.x * 1024u + lq;
    float s = 0.1f * sinf(beta[LAYER]);
    float prevscale = (LAYER == 0) ? 1.0f : (float)(1.0 / sqrt(scal[LAYER - 1]));
    auto ld4 = [&](unsigned j4) -> float4 {
        if (ALIN) return ((const float4*)pin)[j4];
        float4 a;
        a.x = pin[4u * j4 + 0]; a.y = pin[4u * j4 + 1];
        a.z = pin[4u * j4 + 2]; a.w = pin[4u * j4 + 3];
        return a;
    };
    float4 own = ld4(i4);
    tile[lq] = own;
    float4 gv[8];
    #pragma unroll
    for (int p = 19; p >= 12; --p) gv[19 - p] = ld4(i4 ^ (1u << (p - 2)));
    __syncthreads();
    float4 nb = make_float4(0.f, 0.f, 0.f, 0.f);
    #pragma unroll
    for (int u = 0; u < 8; ++u) { nb.x += gv[u].x; nb.y += gv[u].y; nb.z += gv[u].z; nb.w += gv[u].w; }
    #pragma unroll
    for (int p = 11; p >= 2; --p) {
        float4 v = tile[lq ^ (1u << (p - 2))];
        nb.x += v.x; nb.y += v.y; nb.z += v.z; nb.w += v.w;
    }
    nb.x += own.z; nb.y += own.w; nb.z += own.x; nb.w += own.y;
    nb.x += own.y; nb.y += own.x; nb.z += own.w; nb.w += own.z;
    float4 m;
    m.x = prevscale * fmaf(s, nb.x, own.x);
    m.y = prevscale * fmaf(s, nb.y, own.y);
    m.z = prevscale * fmaf(s, nb.z, own.z);
    m.w = prevscale * fmaf(s, nb.w, own.w);
    float4 o;
    if (LAYER < 2) {
        float gn = gamma[LAYER + 1];
        float4 c = ((const float4*)costs)[i4];
        o.x = m.x * cosf(gn * c.x); o.y = m.y * cosf(gn * c.y);
        o.z = m.z * cosf(gn * c.z); o.w = m.w * cosf(gn * c.w);
    } else o = m;
    if (ALOUT) ((float4*)pout)[i4] = o;
    else {
        pout[4u * i4 + 0] = o.x; pout[4u * i4 + 1] = o.y;
        pout[4u * i4 + 2] = o.z; pout[4u * i4 + 3] = o.w;
    }
    double ss = (double)m.x * m.x + (double)m.y * m.y + (double)m.z * m.z + (double)m.w * m.w;
    #pragma unroll
    for (int off = 32; off > 0; off >>= 1) ss += __shfl_down(ss, off);
    int wid = threadIdx.x >> 6;
    if ((threadIdx.x & 63) == 0) dpart[wid] = ss;
    __syncthreads();
    if (threadIdx.x == 0) {
        double tt = 0.0;
        #pragma unroll
        for (int w = 0; w < 16; ++w) tt += dpart[w];
        atomicAdd(&scal[LAYER], tt);
    }
}

template <bool ALIN>
__global__ __launch_bounds__(256) void k_ptop(const float* __restrict__ A,
                                              const double* __restrict__ scal2,
                                              const float* __restrict__ costs,
                                              float* __restrict__ out,
                                              unsigned long long* __restrict__ cand,
                                              unsigned* __restrict__ ctr) {
    __shared__ unsigned long long warr[4];
    __shared__ int lastblk;
    __shared__ unsigned topi[TOPK];
    __shared__ float topc[TOPK];
    const int tid = threadIdx.x;
    float* probs_out = out + 21;
    unsigned b4 = blockIdx.x * 1024u;
    float scale = (float)(1.0 / sqrt(*scal2));
    unsigned long long k[16];
    #pragma unroll
    for (int u = 0; u < 4; ++u) {
        unsigned j4 = b4 + (unsigned)tid + 256u * u;
        float4 v;
        if (ALIN) v = ((const float4*)A)[j4];
        else {
            v.x = A[4u * j4 + 0]; v.y = A[4u * j4 + 1];
            v.z = A[4u * j4 + 2]; v.w = A[4u * j4 + 3];
        }
        float4 p;
        p.x = v.x * scale; p.x *= p.x;
        p.y = v.y * scale; p.y *= p.y;
        p.z = v.z * scale; p.z *= p.z;
        p.w = v.w * scale; p.w *= p.w;
        unsigned e0 = 4u * j4;
        probs_out[e0 + 0] = p.x; probs_out[e0 + 1] = p.y;
        probs_out[e0 + 2] = p.z; probs_out[e0 + 3] = p.w;
        k[4 * u + 0] = ((unsigned long long)__float_as_uint(p.x) << 32) | (unsigned long long)(0xFFFFFFFFu - (e0 + 0));
        k[4 * u + 1] = ((unsigned long long)__float_as_uint(p.y) << 32) | (unsigned long long)(0xFFFFFFFFu - (e0 + 1));
        k[4 * u + 2] = ((unsigned long long)__float_as_uint(p.z) << 32) | (unsigned long long)(0xFFFFFFFFu - (e0 + 2));
        k[4 * u + 3] = ((unsigned long long)__float_as_uint(p.w) << 32) | (unsigned long long)(0xFFFFFFFFu - (e0 + 3));
    }
    for (int r = 0; r < TOPK; ++r) {
        unsigned long long loc = 0ull;
        #pragma unroll
        for (int j = 0; j < 16; ++j) if (k[j] > loc) loc = k[j];
        #pragma unroll
        for (int off = 32; off > 0; off >>= 1) {
            unsigned long long o = __shfl_down(loc, off);
            if (o > loc) loc = o;
        }
        if ((tid & 63) == 0) warr[tid >> 6] = loc;
        __syncthreads();
        unsigned long long win = warr[0];
        if (warr[1] > win) win = warr[1];
        if (warr[2] > win) win = warr[2];
        if (warr[3] > win) win = warr[3];
        __syncthreads();
        #pragma unroll
        for (int j = 0; j < 16; ++j) if (k[j] == win) k[j] = 0ull;
        if (tid == 0) cand[blockIdx.x * TOPK + r] = win;
    }
    __threadfence();
    if (tid == 0) {
        unsigned old = atomicAdd(ctr, 1u);
        lastblk = (old == NB1F - 1) ? 1 : 0;
    }
    __syncthreads();
    if (!lastblk) return;
    __threadfence();
    unsigned long long c2[TOPK];
    #pragma unroll
    for (int u = 0; u < TOPK; ++u) c2[u] = cand[tid + 256 * u];
    for (int r = 0; r < TOPK; ++r) {
        unsigned long long loc = 0ull;
        #pragma unroll
        for (int u = 0; u < TOPK; ++u) if (c2[u] > loc) loc = c2[u];
        #pragma unroll
        for (int off = 32; off > 0; off >>= 1) {
            unsigned long long o = __shfl_down(loc, off);
            if (o > loc) loc = o;
        }
        if ((tid & 63) == 0) warr[tid >> 6] = loc;
        __syncthreads();
        unsigned long long win = warr[0];
        if (warr[1] > win) win = warr[1];
        if (warr[2] > win) win = warr[2];
        if (warr[3] > win) win = warr[3];
        __syncthreads();
        #pragma unroll
        for (int u = 0; u < TOPK; ++u) if (c2[u] == win) c2[u] = 0ull;
        if (tid == 0) topi[r] = 0xFFFFFFFFu - (unsigned)(win & 0xFFFFFFFFull);
        __syncthreads();
    }
    const unsigned S = NSTATES;
    if (tid < TOPK * NV) {
        int kk = tid / NV, vv = tid % NV;
        out[21 + S + (unsigned)tid] = (float)((topi[kk] >> (NV - 1 - vv)) & 1u);
    }
    if (tid < TOPK) {
        float c = costs[topi[tid]];
        topc[tid] = c;
        out[21 + S + TOPK * NV + (unsigned)tid] = c;
    }
    __syncthreads();
    if (tid == 0) {
        int best = 0;
        for (int kk = 1; kk < TOPK; ++kk)
            if (topc[kk] < topc[best]) best = kk;
        unsigned gi = topi[best];
        for (int vv = 0; vv < NV; ++vv)
            out[vv] = (float)((gi >> (NV - 1 - vv)) & 1u);
        out[NV] = topc[best];
    }
}

extern "C" void kernel_launch(void* const* d_in, const int* in_sizes, int n_in,
                              void* d_out_, int out_size, void* d_ws, size_t ws_size,
                              hipStream_t stream) {
    (void)in_sizes; (void)n_in; (void)out_size;
    const float* C     = (const float*)d_in[0];
    const float* beta  = (const float*)d_in[1];
    const float* gamma = (const float*)d_in[2];
    float* out = (float*)d_out_;
    char* ws = (char*)d_ws;
    const size_t S4 = (size_t)NSTATES * sizeof(float);

    double* scal = (double*)ws;                                   // 8 doubles
    unsigned* ctr = (unsigned*)(ws + 64);
    unsigned* flags = (unsigned*)(ws + 256);                      // 256 u32
    unsigned long long* cand = (unsigned long long*)(ws + 2048);  // 20 KB
    float* costs = (float*)(ws + 32768);
    float* A     = (float*)(ws + 32768 + S4);
    const size_t need_full = 32768 + 3 * S4;
    bool wsbig = (ws_size >= need_full);
    float* B = wsbig ? (float*)(ws + 32768 + 2 * S4) : (out + 21);

    // zero scal/ctr/flags (graph-capture-safe)
    hipMemsetAsync(ws, 0, 2048, stream);

    // --- primary: one cooperative kernel with flag barriers ---
    hipError_t err;
    {
        void* args[] = {(void*)&C, (void*)&beta, (void*)&gamma, (void*)&costs,
                        (void*)&A, (void*)&B, (void*)&out, (void*)&scal,
                        (void*)&cand, (void*)&flags, (void*)&ctr};
        const void* fn = wsbig ? (const void*)k_all<true> : (const void*)k_all<false>;
        err = hipLaunchCooperativeKernel(fn, dim3(NBLK), dim3(NTHR), args, 0, stream);
    }
    if (err == hipSuccess) return;

    // --- fallback: validated R4 5-kernel path (bitwise-identical outputs) ---
    k_costs<<<512, 256, 0, stream>>>(C, costs, A, gamma, scal, ctr);
    if (wsbig) {
        k_mix<0, true, true ><<<256, 1024, 0, stream>>>(A, costs, B, gamma, beta, scal);
        k_mix<1, true, true ><<<256, 1024, 0, stream>>>(B, costs, A, gamma, beta, scal);
        k_mix<2, true, true ><<<256, 1024, 0, stream>>>(A, costs, B, gamma, beta, scal);
        k_ptop<true ><<<NB1F, 256, 0, stream>>>(B, scal + 2, costs, out, cand, ctr);
    } else {
        k_mix<0, true, false><<<256, 1024, 0, stream>>>(A, costs, B, gamma, beta, scal);
        k_mix<1, false, true><<<256, 1024, 0, stream>>>(B, costs, A, gamma, beta, scal);
        k_mix<2, true, false><<<256, 1024, 0, stream>>>(A, costs, B, gamma, beta, scal);
        k_ptop<false><<<NB1F, 256, 0, stream>>>(B, scal + 2, costs, out, cand, ctr);
    }
}

// Round 8
// 91.016 us; speedup vs baseline: 7.1215x; 7.1215x over previous
//
#include <hip/hip_runtime.h>
#include <math.h>

#define NV 20
#define NC 64
#define NSTATES (1u << 20)
#define TOPK 10
#define NB1 256              // stage-1 top-k blocks
#define NCAND (NB1 * TOPK)   // 2560

// ---------------------------------------------------------------------------
// costs[i] = sum_c relu(bits(i)·C_c - 1)^2 + 0.1*popcount(i)
// Also emits ph0[i] = 2^-10 * cos(gamma0 * costs[i]) and zeroes the sumsq
// accumulators + top-k ticket counter.
// CHUNKED constraint accumulation (16 c's at a time, bb[4] = 16 VGPRs live)
// so nothing spills under the compiler's 8-wave/64-VGPR heuristic. Per-state
// c-order is ascending 0..63 — bitwise identical to the R4 version (validated
// at absmax 2.98e-8 in R4, and the chunked order re-validated in R6/R7).
// ---------------------------------------------------------------------------
__global__ __launch_bounds__(256) void k_costs(const float* __restrict__ C,
                                               float* __restrict__ costs,
                                               float* __restrict__ ph0,
                                               const float* __restrict__ gamma,
                                               double* __restrict__ scal,
                                               unsigned* __restrict__ ctr) {
    __shared__ float CT[17][NC];    // CT[k][c] = C[c][16-k] (i-bit k+3)
    __shared__ float lowT[8][NC];   // low 3 bits (cols 19,18,17)
    const int tid = threadIdx.x;

    if (blockIdx.x == 0) {
        if (tid < 8) scal[tid] = 0.0;
        if (tid == 8) *ctr = 0u;
    }

    for (int e = tid; e < 17 * NC; e += 256) {
        int k = e / NC, c = e % NC;
        CT[k][c] = C[c * NV + (16 - k)];
    }
    for (int e = tid; e < 8 * NC; e += 256) {
        int m = e >> 6, c = e & 63;
        float v = 0.0f;
        if (m & 1) v += C[c * NV + 19];
        if (m & 2) v += C[c * NV + 18];
        if (m & 4) v += C[c * NV + 17];
        lowT[m][c] = v;
    }
    __syncthreads();

    unsigned t = blockIdx.x * 256u + (unsigned)tid;   // < 2^17, 8 states each
    float g0 = gamma[0];

    float cost[8];
    #pragma unroll
    for (int s = 0; s < 8; ++s)
        cost[s] = 0.1f * (float)__popc(t * 8u + (unsigned)s);

    #pragma unroll
    for (int cc = 0; cc < 4; ++cc) {       // 16 constraints per chunk
        float4 bb[4];
        #pragma unroll
        for (int q = 0; q < 4; ++q) bb[q] = make_float4(-1.f, -1.f, -1.f, -1.f);
        #pragma unroll
        for (int k = 0; k < 17; ++k) {     // i-bit (k+3) == t-bit k
            float bf = (float)((t >> k) & 1u);
            const float4* row = ((const float4*)(&CT[k][0])) + 4 * cc;
            #pragma unroll
            for (int q = 0; q < 4; ++q) {
                float4 cv = row[q];
                bb[q].x = fmaf(bf, cv.x, bb[q].x);
                bb[q].y = fmaf(bf, cv.y, bb[q].y);
                bb[q].z = fmaf(bf, cv.z, bb[q].z);
                bb[q].w = fmaf(bf, cv.w, bb[q].w);
            }
        }
        #pragma unroll
        for (int s = 0; s < 8; ++s) {
            const float4* lrow = ((const float4*)(&lowT[s][0])) + 4 * cc;
            #pragma unroll
            for (int q = 0; q < 4; ++q) {
                float4 lv = lrow[q];
                float4 v;
                v.x = bb[q].x + lv.x; v.y = bb[q].y + lv.y;
                v.z = bb[q].z + lv.z; v.w = bb[q].w + lv.w;
                float r;
                r = fmaxf(v.x, 0.f); cost[s] = fmaf(r, r, cost[s]);
                r = fmaxf(v.y, 0.f); cost[s] = fmaf(r, r, cost[s]);
                r = fmaxf(v.z, 0.f); cost[s] = fmaf(r, r, cost[s]);
                r = fmaxf(v.w, 0.f); cost[s] = fmaf(r, r, cost[s]);
            }
        }
    }

    float4* co = (float4*)(costs + (size_t)t * 8u);
    co[0] = make_float4(cost[0], cost[1], cost[2], cost[3]);
    co[1] = make_float4(cost[4], cost[5], cost[6], cost[7]);
    float ph[8];
    #pragma unroll
    for (int s = 0; s < 8; ++s) ph[s] = 0x1p-10f * cosf(g0 * cost[s]);
    float4* po = (float4*)(ph0 + (size_t)t * 8u);
    po[0] = make_float4(ph[0], ph[1], ph[2], ph[3]);
    po[1] = make_float4(ph[4], ph[5], ph[6], ph[7]);
}

// ---------------------------------------------------------------------------
// LDS-tiled mixer over pre-phased pin (R4 structure):
//   m[i]  = prevscale * (pin[i] + s*sum_{p=19..0} pin[i^(1<<p)])
//   LAYER<2: pout = m*cos(gamma[L+1]*costs);  LAYER==2: pout = m
// Far gathers (p=19..12) now in TWO batches of 4 (gv[4] = 16 VGPRs live)
// to stay under the compiler's register comfort zone — no scratch spill.
// Summation sequence unchanged (g19..g12, t11..t2, own^2, own^1) ->
// bitwise identical to R4.
// ---------------------------------------------------------------------------
template <int LAYER, bool ALIN, bool ALOUT>
__global__ __launch_bounds__(1024, 4) void k_mix(const float* __restrict__ pin,
                                                 const float* __restrict__ costs,
                                                 float* __restrict__ pout,
                                                 const float* __restrict__ gamma,
                                                 const float* __restrict__ beta,
                                                 double* __restrict__ scal) {
    __shared__ float4 tile[1024];     // 16 KB
    __shared__ double dpart[16];
    const unsigned lq = threadIdx.x;               // local quad 0..1023
    const unsigned i4 = blockIdx.x * 1024u + lq;   // global quad < 2^18
    float s = 0.1f * sinf(beta[LAYER]);
    float prevscale = (LAYER == 0) ? 1.0f : (float)(1.0 / sqrt(scal[LAYER - 1]));

    auto ld4 = [&](unsigned j4) -> float4 {
        if (ALIN) return ((const float4*)pin)[j4];
        float4 a;
        a.x = pin[4u * j4 + 0]; a.y = pin[4u * j4 + 1];
        a.z = pin[4u * j4 + 2]; a.w = pin[4u * j4 + 3];
        return a;
    };

    float4 own = ld4(i4);
    tile[lq] = own;

    // far gathers batch 1: p = 19..16 (quad-shift 17..14)
    float4 gv[4];
    #pragma unroll
    for (int u = 0; u < 4; ++u) gv[u] = ld4(i4 ^ (1u << (17 - u)));

    __syncthreads();

    float4 nb = make_float4(0.f, 0.f, 0.f, 0.f);
    #pragma unroll
    for (int u = 0; u < 4; ++u) {      // p = 19..16 descending
        nb.x += gv[u].x; nb.y += gv[u].y; nb.z += gv[u].z; nb.w += gv[u].w;
    }
    // far gathers batch 2: p = 15..12 (quad-shift 13..10)
    #pragma unroll
    for (int u = 0; u < 4; ++u) gv[u] = ld4(i4 ^ (1u << (13 - u)));
    #pragma unroll
    for (int u = 0; u < 4; ++u) {      // p = 15..12 descending
        nb.x += gv[u].x; nb.y += gv[u].y; nb.z += gv[u].z; nb.w += gv[u].w;
    }
    #pragma unroll
    for (int p = 11; p >= 2; --p) {    // local flips from LDS
        float4 v = tile[lq ^ (1u << (p - 2))];
        nb.x += v.x; nb.y += v.y; nb.z += v.z; nb.w += v.w;
    }
    // p = 1: element e gets own element e^2
    nb.x += own.z; nb.y += own.w; nb.z += own.x; nb.w += own.y;
    // p = 0: element e gets own element e^1
    nb.x += own.y; nb.y += own.x; nb.z += own.w; nb.w += own.z;

    float4 m;
    m.x = prevscale * fmaf(s, nb.x, own.x);
    m.y = prevscale * fmaf(s, nb.y, own.y);
    m.z = prevscale * fmaf(s, nb.z, own.z);
    m.w = prevscale * fmaf(s, nb.w, own.w);

    float4 o;
    if (LAYER < 2) {
        float gn = gamma[LAYER + 1];
        float4 c = ((const float4*)costs)[i4];
        o.x = m.x * cosf(gn * c.x);
        o.y = m.y * cosf(gn * c.y);
        o.z = m.z * cosf(gn * c.z);
        o.w = m.w * cosf(gn * c.w);
    } else {
        o = m;
    }
    if (ALOUT) {
        ((float4*)pout)[i4] = o;
    } else {
        pout[4u * i4 + 0] = o.x; pout[4u * i4 + 1] = o.y;
        pout[4u * i4 + 2] = o.z; pout[4u * i4 + 3] = o.w;
    }

    double ss = (double)m.x * m.x + (double)m.y * m.y +
                (double)m.z * m.z + (double)m.w * m.w;
    #pragma unroll
    for (int off = 32; off > 0; off >>= 1) ss += __shfl_down(ss, off);
    int wid = threadIdx.x >> 6;
    if ((threadIdx.x & 63) == 0) dpart[wid] = ss;
    __syncthreads();
    if (threadIdx.x == 0) {
        double tt = 0.0;
        #pragma unroll
        for (int w = 0; w < 16; ++w) tt += dpart[w];
        atomicAdd(&scal[LAYER], tt);
    }
}

// ---------------------------------------------------------------------------
// Fused probs + top-k stage 1 + (last block) stage 2 merge & readout.
// Identical to R4 (validated).
// ---------------------------------------------------------------------------
template <bool ALIN>
__global__ __launch_bounds__(256) void k_ptop(const float* __restrict__ A,
                                              const double* __restrict__ scal2,
                                              const float* __restrict__ costs,
                                              float* __restrict__ out,
                                              unsigned long long* __restrict__ cand,
                                              unsigned* __restrict__ ctr) {
    __shared__ unsigned long long warr[4];
    __shared__ int lastblk;
    __shared__ unsigned topi[TOPK];
    __shared__ float topc[TOPK];
    const int tid = threadIdx.x;
    float* probs_out = out + 21;
    unsigned b4 = blockIdx.x * 1024u;   // float4 base
    float scale = (float)(1.0 / sqrt(*scal2));

    unsigned long long k[16];
    #pragma unroll
    for (int u = 0; u < 4; ++u) {
        unsigned j4 = b4 + (unsigned)tid + 256u * u;
        float4 v;
        if (ALIN) v = ((const float4*)A)[j4];
        else {
            v.x = A[4u * j4 + 0]; v.y = A[4u * j4 + 1];
            v.z = A[4u * j4 + 2]; v.w = A[4u * j4 + 3];
        }
        float4 p;
        p.x = v.x * scale; p.x *= p.x;
        p.y = v.y * scale; p.y *= p.y;
        p.z = v.z * scale; p.z *= p.z;
        p.w = v.w * scale; p.w *= p.w;
        unsigned e0 = 4u * j4;
        probs_out[e0 + 0] = p.x; probs_out[e0 + 1] = p.y;
        probs_out[e0 + 2] = p.z; probs_out[e0 + 3] = p.w;
        k[4 * u + 0] = ((unsigned long long)__float_as_uint(p.x) << 32) | (unsigned long long)(0xFFFFFFFFu - (e0 + 0));
        k[4 * u + 1] = ((unsigned long long)__float_as_uint(p.y) << 32) | (unsigned long long)(0xFFFFFFFFu - (e0 + 1));
        k[4 * u + 2] = ((unsigned long long)__float_as_uint(p.z) << 32) | (unsigned long long)(0xFFFFFFFFu - (e0 + 2));
        k[4 * u + 3] = ((unsigned long long)__float_as_uint(p.w) << 32) | (unsigned long long)(0xFFFFFFFFu - (e0 + 3));
    }

    for (int r = 0; r < TOPK; ++r) {
        unsigned long long loc = 0ull;
        #pragma unroll
        for (int j = 0; j < 16; ++j) if (k[j] > loc) loc = k[j];
        #pragma unroll
        for (int off = 32; off > 0; off >>= 1) {
            unsigned long long o = __shfl_down(loc, off);
            if (o > loc) loc = o;
        }
        if ((tid & 63) == 0) warr[tid >> 6] = loc;
        __syncthreads();
        unsigned long long win = warr[0];
        if (warr[1] > win) win = warr[1];
        if (warr[2] > win) win = warr[2];
        if (warr[3] > win) win = warr[3];
        __syncthreads();
        #pragma unroll
        for (int j = 0; j < 16; ++j) if (k[j] == win) k[j] = 0ull;
        if (tid == 0) cand[blockIdx.x * TOPK + r] = win;
    }

    // ---- last-block ticket ----
    __threadfence();
    if (tid == 0) {
        unsigned old = atomicAdd(ctr, 1u);
        lastblk = (old == NB1 - 1) ? 1 : 0;
    }
    __syncthreads();
    if (!lastblk) return;
    __threadfence();

    // ---- stage 2: merge NCAND candidates with this one block ----
    unsigned long long c2[TOPK];
    #pragma unroll
    for (int u = 0; u < TOPK; ++u) c2[u] = cand[tid + 256 * u];

    for (int r = 0; r < TOPK; ++r) {
        unsigned long long loc = 0ull;
        #pragma unroll
        for (int u = 0; u < TOPK; ++u) if (c2[u] > loc) loc = c2[u];
        #pragma unroll
        for (int off = 32; off > 0; off >>= 1) {
            unsigned long long o = __shfl_down(loc, off);
            if (o > loc) loc = o;
        }
        if ((tid & 63) == 0) warr[tid >> 6] = loc;
        __syncthreads();
        unsigned long long win = warr[0];
        if (warr[1] > win) win = warr[1];
        if (warr[2] > win) win = warr[2];
        if (warr[3] > win) win = warr[3];
        __syncthreads();
        #pragma unroll
        for (int u = 0; u < TOPK; ++u) if (c2[u] == win) c2[u] = 0ull;
        if (tid == 0) topi[r] = 0xFFFFFFFFu - (unsigned)(win & 0xFFFFFFFFull);
        __syncthreads();
    }

    const unsigned S = NSTATES;
    if (tid < TOPK * NV) {
        int kk = tid / NV, vv = tid % NV;
        out[21 + S + (unsigned)tid] = (float)((topi[kk] >> (NV - 1 - vv)) & 1u);
    }
    if (tid < TOPK) {
        float c = costs[topi[tid]];
        topc[tid] = c;
        out[21 + S + TOPK * NV + (unsigned)tid] = c;
    }
    __syncthreads();
    if (tid == 0) {
        int best = 0;
        for (int kk = 1; kk < TOPK; ++kk)
            if (topc[kk] < topc[best]) best = kk;
        unsigned gi = topi[best];
        for (int vv = 0; vv < NV; ++vv)
            out[vv] = (float)((gi >> (NV - 1 - vv)) & 1u);
        out[NV] = topc[best];
    }
}

extern "C" void kernel_launch(void* const* d_in, const int* in_sizes, int n_in,
                              void* d_out_, int out_size, void* d_ws, size_t ws_size,
                              hipStream_t stream) {
    (void)in_sizes; (void)n_in; (void)out_size;
    const float* C     = (const float*)d_in[0];
    const float* beta  = (const float*)d_in[1];
    const float* gamma = (const float*)d_in[2];
    float* out = (float*)d_out_;
    char* ws = (char*)d_ws;
    const size_t S4 = (size_t)NSTATES * sizeof(float);

    double* scal = (double*)ws;                                   // 8 doubles
    unsigned* ctr = (unsigned*)(ws + 64);
    unsigned long long* cand = (unsigned long long*)(ws + 1024);  // 20 KB
    float* costs = (float*)(ws + 32768);
    float* A     = (float*)(ws + 32768 + S4);                     // ph0 / pm2
    const size_t need_full = 32768 + 3 * S4;
    bool wsbig = (ws_size >= need_full);
    float* B = wsbig ? (float*)(ws + 32768 + 2 * S4) : (out + 21); // pm1 / m2

    // costs + layer-0 phase array (A = ph0)
    k_costs<<<512, 256, 0, stream>>>(C, costs, A, gamma, scal, ctr);

    // mix0: A(ph0) -> B(pm1);  mix1: B(pm1) -> A(pm2);  mix2: A(pm2) -> B(m2)
    if (wsbig) {
        k_mix<0, true, true ><<<256, 1024, 0, stream>>>(A, costs, B, gamma, beta, scal);
        k_mix<1, true, true ><<<256, 1024, 0, stream>>>(B, costs, A, gamma, beta, scal);
        k_mix<2, true, true ><<<256, 1024, 0, stream>>>(A, costs, B, gamma, beta, scal);
        k_ptop<true ><<<NB1, 256, 0, stream>>>(B, scal + 2, costs, out, cand, ctr);
    } else {
        k_mix<0, true, false><<<256, 1024, 0, stream>>>(A, costs, B, gamma, beta, scal);
        k_mix<1, false, true><<<256, 1024, 0, stream>>>(B, costs, A, gamma, beta, scal);
        k_mix<2, true, false><<<256, 1024, 0, stream>>>(A, costs, B, gamma, beta, scal);
        k_ptop<false><<<NB1, 256, 0, stream>>>(B, scal + 2, costs, out, cand, ctr);
    }
}